// Round 2
// 757.243 us; speedup vs baseline: 1.0920x; 1.0920x over previous
//
#include <hip/hip_runtime.h>
#include <stdint.h>

// LatentODE fused: B=8192, T=100, D=44, NH=64, L=8.
// 4 waves per 16-batch tile (512 blocks x 256 thr): each wave owns one
// 16-row tau-tile of every 64-row layer (RNN cell, f-net L1/L2, decoder d1).
// Activations exchanged cross-wave via the LDS repack layout + lgkmcnt-only
// barrier (global prefetch stays in flight). 3 rotating exchange buffers ->
// one barrier per exchange, race-free. Accumulate order bit-identical to the
// 1-wave version. Per-wave partials -> tiny reduce kernel.
// (Resubmission: previous round failed at container level, no kernel signal.)

constexpr int B_ = 8192, T_ = 100, D_ = 44, NH_ = 64, L_ = 8;

typedef __bf16 bf16x8 __attribute__((ext_vector_type(8)));
typedef float f32x4 __attribute__((ext_vector_type(4)));
typedef uint32_t u32x4 __attribute__((ext_vector_type(4)));
typedef uint32_t u32x2 __attribute__((ext_vector_type(2)));

__device__ __forceinline__ float fexp2(float x) { return __builtin_amdgcn_exp2f(x); }
__device__ __forceinline__ float frcp(float x) { return __builtin_amdgcn_rcpf(x); }
__device__ __forceinline__ float fexp(float x) { return fexp2(x * 1.44269504088896341f); }
__device__ __forceinline__ float tanh_f(float x) {
  float e = fexp2(x * 2.88539008177792681f);
  return 1.0f - 2.0f * frcp(e + 1.0f);
}
__device__ __forceinline__ float elu_f(float x) { return x > 0.0f ? x : (fexp(x) - 1.0f); }
__device__ __forceinline__ uint32_t f2bs(float x) {
  return (uint32_t)__builtin_bit_cast(unsigned short, (__bf16)x);
}
__device__ __forceinline__ uint32_t pk(float lo, float hi) { return f2bs(lo) | (f2bs(hi) << 16); }
__device__ __forceinline__ uint32_t sh(uint32_t v, int s) { return (uint32_t)__shfl((int)v, s, 64); }
__device__ __forceinline__ f32x4 mfma16(bf16x8 a, bf16x8 b, f32x4 c) {
  return __builtin_amdgcn_mfma_f32_16x16x32_bf16(a, b, c, 0, 0, 0);
}
__device__ __forceinline__ bf16x8 pack8(float a, float b, float c, float d,
                                        float e, float f, float g, float h) {
  u32x4 u = {pk(a, b), pk(c, d), pk(e, f), pk(g, h)};
  return __builtin_bit_cast(bf16x8, u);
}
__device__ __forceinline__ float f4get(const float4& f, int i) {
  return i == 0 ? f.x : (i == 1 ? f.y : (i == 2 ? f.z : f.w));
}

// Cross-wave exchange barrier. lgkmcnt-only drain: LDS writes are visible,
// but outstanding global (prefetch) loads stay in flight across the barrier
// (unlike __syncthreads()'s conservative vmcnt(0)). Memory clobbers pin
// compiler ordering of the DS ops around the barrier.
__device__ __forceinline__ void xbar() {
  asm volatile("s_waitcnt lgkmcnt(0)" ::: "memory");
  __builtin_amdgcn_s_barrier();
  asm volatile("" ::: "memory");
}

// Exchange layout: word = 36*c + kpair (kpair = row/2), stride 36 dodges
// bank aliasing. Wave w writes its C-tile rows 16w+4q+r (col c) as one
// ds_write_b64 (2-way bank alias = free); every wave reads full-K B-frags
// as 2x ds_read_b128 (1KB/wave = mandatory 8-deep aliasing, near peak).
__device__ __forceinline__ void ex_write(uint32_t* ex, int c, int q, int w, f32x4 e) {
  u32x2 v = {pk(e[0], e[1]), pk(e[2], e[3])};
  *(u32x2*)(ex + 36 * c + 8 * w + 2 * q) = v;
}
__device__ __forceinline__ void ex_read(const uint32_t* ex, int c, int q, bf16x8* bh) {
#pragma unroll
  for (int ks = 0; ks < 2; ++ks) {
    u32x4 r = *(const u32x4*)(ex + 36 * c + 16 * ks + 4 * q);
    bh[ks] = __builtin_bit_cast(bf16x8, r);
  }
}

// z (rows 0-7 live on lanes q<2) -> B-frag; row 8 := 1.0 (bias row).
__device__ __forceinline__ bf16x8 build_bz(f32x4 z, int c, int q) {
  uint32_t p01 = pk(z[0], z[1]), p23 = pk(z[2], z[3]);
  u32x4 u = {sh(p01, c), sh(p23, c), sh(p01, c + 16), sh(p23, c + 16)};
  if (q == 1) u[0] = 0x3f80u;  // k=8 -> 1.0, k=9 -> 0
  return __builtin_bit_cast(bf16x8, u);
}

__global__ __launch_bounds__(256) void fused_kernel(
    const float* __restrict__ x, const float* __restrict__ mask,
    const float* __restrict__ eps,
    const float* __restrict__ Wi2h, const float* __restrict__ bi2h,
    const float* __restrict__ Wh2o, const float* __restrict__ bh2o,
    const float* __restrict__ Wf1, const float* __restrict__ bf1,
    const float* __restrict__ Wf2, const float* __restrict__ bf2,
    const float* __restrict__ Wf3, const float* __restrict__ bf3,
    const float* __restrict__ Wd1, const float* __restrict__ bd1,
    const float* __restrict__ Wd2, const float* __restrict__ bd2,
    float* __restrict__ part) {
  const int tid = threadIdx.x;
  const int w = tid >> 6;        // wave id = owned tau tile
  const int lane = tid & 63;
  const int c = lane & 15, q = lane >> 4;
  const int r0 = blockIdx.x * 16;

  __shared__ __align__(16) uint32_t exA[576];
  __shared__ __align__(16) uint32_t exB[576];
  __shared__ __align__(16) uint32_t exC[576];
  __shared__ float redbuf[4];

  // ================= Phase 1: backward RNN scan =================
  // State rows: [h 0..63 ; obs 64..107 ; bias 108]. Wave w owns h-rows
  // 16w..16w+15; A-frags only for its own tau.
  bf16x8 Ai[4];
#pragma unroll
  for (int ks = 0; ks < 4; ++ks) {
    bf16x8 f;
    const int m = 16 * w + c;
#pragma unroll
    for (int i = 0; i < 8; ++i) {
      const int k = 32 * ks + 8 * q + i;
      float v = 0.0f;
      if (k < 64) v = Wi2h[(44 + k) * 64 + m];
      else if (k < 108) v = Wi2h[(k - 64) * 64 + m];
      else if (k == 108) v = bi2h[m];
      f[i] = (__bf16)v;
    }
    Ai[ks] = f;
  }
  bf16x8 Ah2o[2];
#pragma unroll
  for (int ks = 0; ks < 2; ++ks) {
    bf16x8 f;
#pragma unroll
    for (int i = 0; i < 8; ++i) f[i] = (__bf16)Wh2o[(32 * ks + 8 * q + i) * 16 + c];
    Ah2o[ks] = f;
  }
  f32x4 bo;
#pragma unroll
  for (int r = 0; r < 4; ++r) bo[r] = bh2o[4 * q + r];

  const float* xrowbase = x + (size_t)(r0 + c) * T_ * D_;
  const float* mrowbase = mask + (size_t)(r0 + c) * T_ * D_;

  // obs B-frags are needed by every wave's MFMA (full K) -> each wave loads
  // redundantly; the 4 waves hit the same L1 lines in lockstep.
  auto load_obs = [&](int t, float4& a0, float4& a1, float4& b0, float4& b1,
                      float4& ma0, float4& ma1, float4& mb0, float4& mb1) {
    const float4* xr = (const float4*)(xrowbase + (size_t)t * D_);
    const float4* mr = (const float4*)(mrowbase + (size_t)t * D_);
    a0 = xr[2 * q]; a1 = xr[2 * q + 1]; ma0 = mr[2 * q]; ma1 = mr[2 * q + 1];
    float4 zz = {0.f, 0.f, 0.f, 0.f};
    b0 = zz; b1 = zz; mb0 = zz; mb1 = zz;
    if (q == 0) { b0 = xr[8]; b1 = xr[9]; mb0 = mr[8]; mb1 = mr[9]; }
    else if (q == 1) { b0 = xr[10]; mb0 = mr[10]; }
  };

  f32x4 hc = {0.f, 0.f, 0.f, 0.f};
  float4 a0, a1, b0, b1, ma0, ma1, mb0, mb1;
  load_obs(T_ - 1, a0, a1, b0, b1, ma0, ma1, mb0, mb1);

#pragma unroll 1
  for (int s = 0; s < T_; ++s) {
    // Buffer parity per step: write/read s&1; reuse of a buffer is always
    // separated by the intervening step's barrier -> race-free.
    uint32_t* ex = (s & 1) ? exB : exA;
    ex_write(ex, c, q, w, hc);

    const int t = T_ - 1 - s;
    float4 ca0 = a0, ca1 = a1, cb0 = b0, cb1 = b1;
    float4 cm0 = ma0, cm1 = ma1, cn0 = mb0, cn1 = mb1;
    if (t > 0) load_obs(t - 1, a0, a1, b0, b1, ma0, ma1, mb0, mb1);

    // Build obs frags while waiting for the other waves.
    bf16x8 o2 = pack8(ca0.x * cm0.x, ca0.y * cm0.y, ca0.z * cm0.z, ca0.w * cm0.w,
                      ca1.x * cm1.x, ca1.y * cm1.y, ca1.z * cm1.z, ca1.w * cm1.w);
    const float e44 = (q == 1) ? 1.0f : cb1.x * cn1.x;  // bias row k=108
    bf16x8 o3 = pack8(cb0.x * cn0.x, cb0.y * cn0.y, cb0.z * cn0.z, cb0.w * cn0.w,
                      e44, cb1.y * cn1.y, cb1.z * cn1.z, cb1.w * cn1.w);

    xbar();
    bf16x8 bh[2];
    ex_read(ex, c, q, bh);

    f32x4 zero = {0.f, 0.f, 0.f, 0.f};
    f32x4 acc = mfma16(Ai[0], bh[0], zero);
    acc = mfma16(Ai[1], bh[1], acc);
    acc = mfma16(Ai[2], o2, acc);
    acc = mfma16(Ai[3], o3, acc);
#pragma unroll
    for (int r = 0; r < 4; ++r) hc[r] = tanh_f(acc[r]);
  }

  // ================= Phase 2: head, z0, KL (redundant per wave) ==========
  // T_ even -> exA free this parity.
  ex_write(exA, c, q, w, hc);
  xbar();
  bf16x8 bhF[2];
  ex_read(exA, c, q, bhF);
  f32x4 o = mfma16(Ah2o[1], bhF[1], mfma16(Ah2o[0], bhF[0], bo));

  float lv[4];
#pragma unroll
  for (int r = 0; r < 4; ++r)
    lv[r] = __int_as_float(__shfl(__float_as_int(o[r]), lane + 32, 64));

  float klt = 0.0f;
  f32x4 z = {};
  if (q < 2) {
    const float4 ev = *(const float4*)(eps + (size_t)(r0 + c) * 8 + 4 * q);
#pragma unroll
    for (int r = 0; r < 4; ++r) {
      const float m = o[r];
      z[r] = f4get(ev, r) * fexp(0.5f * lv[r]) + m;
      klt += -0.5f * lv[r] + (fexp(lv[r]) + m * m) * 0.5f - 0.5f;
    }
  }
  klt += __shfl_xor(klt, 1);  klt += __shfl_xor(klt, 2);
  klt += __shfl_xor(klt, 4);  klt += __shfl_xor(klt, 8);
  klt += __shfl_xor(klt, 16); klt += __shfl_xor(klt, 32);

  __builtin_amdgcn_sched_barrier(0);  // keep phase-3 weight loads below

  // ================= Phase 3 weights (own tau only) =================
  bf16x8 A1, A2[2], A3[2], Ad1, Ad2[2];
  {
    bf16x8 f1, fd;
#pragma unroll
    for (int i = 0; i < 8; ++i) {
      const int k = 8 * q + i;
      f1[i] = (__bf16)(k < 8 ? Wf1[k * 64 + 16 * w + c] : (k == 8 ? bf1[16 * w + c] : 0.0f));
      fd[i] = (__bf16)(k < 8 ? Wd1[k * 64 + 16 * w + c] : (k == 8 ? bd1[16 * w + c] : 0.0f));
    }
    A1 = f1; Ad1 = fd;
  }
#pragma unroll
  for (int ks = 0; ks < 2; ++ks) {
    bf16x8 g;
#pragma unroll
    for (int i = 0; i < 8; ++i) g[i] = (__bf16)Wf2[(32 * ks + 8 * q + i) * 64 + 16 * w + c];
    A2[ks] = g;
  }
#pragma unroll
  for (int ks = 0; ks < 2; ++ks) {
    bf16x8 f;
#pragma unroll
    for (int i = 0; i < 8; ++i)
      f[i] = (__bf16)((c < 8) ? Wf3[(32 * ks + 8 * q + i) * 8 + c] : 0.0f);
    A3[ks] = f;
  }
#pragma unroll
  for (int ks = 0; ks < 2; ++ks) {
    bf16x8 f;
    const int m = 16 * w + c;
#pragma unroll
    for (int i = 0; i < 8; ++i)
      f[i] = (__bf16)((m < 44) ? Wd2[(32 * ks + 8 * q + i) * 44 + m] : 0.0f);
    Ad2[ks] = f;
  }
  f32x4 b2_, b3_, bd2_;
#pragma unroll
  for (int r = 0; r < 4; ++r) b2_[r] = bf2[16 * w + 4 * q + r];
#pragma unroll
  for (int r = 0; r < 4; ++r) b3_[r] = (q < 2) ? bf3[4 * q + r] : 0.0f;
#pragma unroll
  for (int r = 0; r < 4; ++r) {
    const int d = 16 * w + 4 * q + r;
    bd2_[r] = (d < 44) ? bd2[d] : 0.0f;
  }

  // feval: L1 on own tau, exchange (exA), L2 on own tau, exchange (exB),
  // L3 redundant on every wave (bit-identical inputs -> identical z).
  auto feval = [&](bf16x8 bz) -> f32x4 {
    f32x4 zero = {0.f, 0.f, 0.f, 0.f};
    f32x4 h = mfma16(A1, bz, zero);
#pragma unroll
    for (int r = 0; r < 4; ++r) h[r] = elu_f(h[r]);
    ex_write(exA, c, q, w, h);
    xbar();
    bf16x8 bh[2];
    ex_read(exA, c, q, bh);
    f32x4 g = mfma16(A2[1], bh[1], mfma16(A2[0], bh[0], b2_));
#pragma unroll
    for (int r = 0; r < 4; ++r) g[r] = elu_f(g[r]);
    ex_write(exB, c, q, w, g);
    xbar();
    bf16x8 bg[2];
    ex_read(exB, c, q, bg);
    return mfma16(A3[1], bg[1], mfma16(A3[0], bg[0], b3_));
  };

  // NLL x/mask loads: wave w<3 covers output dims 16w+4q (splits 3-ways).
  auto load_xm = [&](int t, float4& xv, float4& mv) {
    const int d0 = 16 * w + 4 * q;
    if (w < 3 && d0 < 44) {
      const size_t off = (size_t)(r0 + c) * T_ * D_ + (size_t)t * D_ + d0;
      xv = *(const float4*)(x + off);
      mv = *(const float4*)(mask + off);
    }
  };

  const float dt = 1.0f / (float)(T_ - 1);
  const float hdt = 0.5f * dt;
  float qacc = 0.0f;

  float4 xc = {0.f, 0.f, 0.f, 0.f}, mc = xc, xn = xc, mn = xc;
  load_xm(0, xc, mc);

#pragma unroll 1
  for (int t = 0; t < T_; ++t) {
    if (t < T_ - 1) load_xm(t + 1, xn, mn);  // prefetch rides across xbars

    bf16x8 bz = build_bz(z, c, q);

    // ---- decoder on z_t: d1 on own tau, exchange via exC, d2 on w<3 ----
    f32x4 zero = {0.f, 0.f, 0.f, 0.f};
    f32x4 hd = mfma16(Ad1, bz, zero);
#pragma unroll
    for (int r = 0; r < 4; ++r) hd[r] = fmaxf(hd[r], 0.0f);
    ex_write(exC, c, q, w, hd);
    xbar();
    if (w < 3) {
      bf16x8 bhd[2];
      ex_read(exC, c, q, bhd);
      f32x4 p = mfma16(Ad2[1], bhd[1], mfma16(Ad2[0], bhd[0], bd2_));
      if (16 * w + 4 * q < 44) {
#pragma unroll
        for (int r = 0; r < 4; ++r) {
          const float xa = f4get(xc, r), ma = f4get(mc, r);
          const float mx = xa * ma;
          const float upd = (mx != 0.0f) ? mx : p[r];
          const float df = xa - upd;
          qacc += df * df;
        }
      }
    }

    // ---- RK4 advance ----
    if (t < T_ - 1) {
      f32x4 k1 = feval(bz);
      f32x4 zt;
#pragma unroll
      for (int r = 0; r < 4; ++r) zt[r] = z[r] + hdt * k1[r];
      f32x4 k2 = feval(build_bz(zt, c, q));
#pragma unroll
      for (int r = 0; r < 4; ++r) zt[r] = z[r] + hdt * k2[r];
      f32x4 k3 = feval(build_bz(zt, c, q));
#pragma unroll
      for (int r = 0; r < 4; ++r) zt[r] = z[r] + dt * k3[r];
      f32x4 k4 = feval(build_bz(zt, c, q));
#pragma unroll
      for (int r = 0; r < 4; ++r)
        z[r] += (dt / 6.0f) * (k1[r] + 2.0f * (k2[r] + k3[r]) + k4[r]);
      xc = xn; mc = mn;
    }
  }

  // ---- block partial: kl + scaled SSE ----
  float tot = qacc * (0.5f / 0.09f);
  tot += __shfl_xor(tot, 1);  tot += __shfl_xor(tot, 2);
  tot += __shfl_xor(tot, 4);  tot += __shfl_xor(tot, 8);
  tot += __shfl_xor(tot, 16); tot += __shfl_xor(tot, 32);
  if (lane == 0) redbuf[w] = tot;
  xbar();
  if (tid == 0)
    part[blockIdx.x] = redbuf[0] + redbuf[1] + redbuf[2] + redbuf[3] + klt;
}

// =================== final reduction: 512 partials -> loss ===================
__global__ __launch_bounds__(512) void reduce_kernel(const float* __restrict__ part,
                                                     float* __restrict__ out) {
  __shared__ float s[8];
  const int tid = threadIdx.x;
  float v = part[tid];
  v += __shfl_xor(v, 1);  v += __shfl_xor(v, 2);
  v += __shfl_xor(v, 4);  v += __shfl_xor(v, 8);
  v += __shfl_xor(v, 16); v += __shfl_xor(v, 32);
  if ((tid & 63) == 0) s[tid >> 6] = v;
  __syncthreads();
  if (tid == 0) {
    float acc = 0.0f;
#pragma unroll
    for (int i = 0; i < 8; ++i) acc += s[i];
    const float c0 = 0.28503427112126353f;  // -0.5*(log(2pi)+2*log(0.3))
    out[0] = acc * (1.0f / (float)B_) - (float)(T_ * D_) * c0;
  }
}

extern "C" void kernel_launch(void* const* d_in, const int* in_sizes, int n_in,
                              void* d_out, int out_size, void* d_ws, size_t ws_size,
                              hipStream_t stream) {
  const float* x    = (const float*)d_in[0];
  const float* mask = (const float*)d_in[1];
  const float* eps  = (const float*)d_in[2];
  const float* Wi2h = (const float*)d_in[3];
  const float* bi2h = (const float*)d_in[4];
  const float* Wh2o = (const float*)d_in[5];
  const float* bh2o = (const float*)d_in[6];
  const float* Wf1  = (const float*)d_in[7];
  const float* bf1  = (const float*)d_in[8];
  const float* Wf2  = (const float*)d_in[9];
  const float* bf2  = (const float*)d_in[10];
  const float* Wf3  = (const float*)d_in[11];
  const float* bf3  = (const float*)d_in[12];
  const float* Wd1  = (const float*)d_in[13];
  const float* bd1  = (const float*)d_in[14];
  const float* Wd2  = (const float*)d_in[15];
  const float* bd2  = (const float*)d_in[16];

  float* loss = (float*)d_out;
  float* part = (float*)d_ws;  // 512 floats

  fused_kernel<<<dim3(B_ / 16), dim3(256), 0, stream>>>(
      x, mask, eps, Wi2h, bi2h, Wh2o, bh2o, Wf1, bf1, Wf2, bf2, Wf3, bf3,
      Wd1, bd1, Wd2, bd2, part);
  reduce_kernel<<<dim3(1), dim3(512), 0, stream>>>(part, loss);
}